// Round 1
// baseline (2420.074 us; speedup 1.0000x reference)
//
#include <hip/hip_runtime.h>

#define HID 256
#define EF  64
#define KIN 320      // HID + EF
#define NC  4096
#define NE  65536
#define BSZ 4
#define EPSV 1e-5f

// edge kernel tiling
#define ME   32      // edges per block
#define XSTR 324     // LDS stride for X tile (floats), 16B-aligned, breaks bank pow2
#define HSTR 260     // LDS stride for hidden tile
// node kernel tiling
#define MN    16     // rows per block
#define XSTR2 516    // LDS stride for [cell_x | agg] tile

// pick float4 component with constant index (folds after unroll)
#define F4C(v, kk) ((kk) == 0 ? (v).x : (kk) == 1 ? (v).y : (kk) == 2 ? (v).z : (v).w)

__global__ void zero_kernel(float4* __restrict__ p, int n4) {
    int i = blockIdx.x * blockDim.x + threadIdx.x;
    int stride = gridDim.x * blockDim.x;
    float4 z = make_float4(0.f, 0.f, 0.f, 0.f);
    for (; i < n4; i += stride) p[i] = z;
}

__global__ __launch_bounds__(256)
void count_kernel(const int* __restrict__ eidx, float* __restrict__ counts) {
    int g = blockIdx.x * 256 + threadIdx.x;     // g in [0, BSZ*NE)
    int d = eidx[(size_t)g * 2 + 1];
    d = min(max(d, 0), NC - 1);
    int b = g >> 16;                            // NE = 65536
    atomicAdd(&counts[b * NC + d], 1.0f);
}

__global__ __launch_bounds__(256)
void edge_kernel(const float* __restrict__ cell_x,
                 const int*   __restrict__ eidx,
                 const float* __restrict__ eattr,
                 const float* __restrict__ W1, const float* __restrict__ b1,
                 const float* __restrict__ W2, const float* __restrict__ b2,
                 float* __restrict__ agg) {
    __shared__ float xs[ME * XSTR];   // X tile; later reused for hidden tile
    __shared__ int s_src[ME], s_dst[ME];

    const int tid = threadIdx.x;
    const int b   = blockIdx.x >> 11;            // 2048 blocks per batch
    const int e0  = (blockIdx.x & 2047) * ME;

    if (tid < ME) {
        int2 v = ((const int2*)eidx)[(size_t)b * NE + e0 + tid];
        s_src[tid] = min(max(v.x, 0), NC - 1);
        s_dst[tid] = min(max(v.y, 0), NC - 1);
    }
    __syncthreads();

    // gather X = [src_x | edge_attr]: wave wv loads edges wv*8 .. wv*8+7
    const int wv = tid >> 6, ln = tid & 63;
    #pragma unroll
    for (int i = 0; i < 8; ++i) {
        int m = wv * 8 + i;
        const float4* crow = (const float4*)(cell_x + ((size_t)b * NC + s_src[m]) * HID);
        ((float4*)&xs[m * XSTR])[ln] = crow[ln];                 // 64 lanes * 4 = 256 floats
        if (ln < 16) {
            const float4* arow = (const float4*)(eattr + ((size_t)b * NE + e0 + m) * EF);
            ((float4*)&xs[m * XSTR + HID])[ln] = arow[ln];       // 64 floats
        }
    }
    __syncthreads();

    const int tn = tid & 31, tm = tid >> 5;      // 32 col-groups x 8 row-groups
    // ---- GEMM1: hidden = relu(X @ W1 + b1), K=320 ----
    float acc[4][8];
    #pragma unroll
    for (int mi = 0; mi < 4; ++mi)
        #pragma unroll
        for (int ni = 0; ni < 8; ++ni)
            acc[mi][ni] = b1[tn * 8 + ni];

    for (int k0 = 0; k0 < KIN; k0 += 4) {
        float4 a4[4];
        #pragma unroll
        for (int mi = 0; mi < 4; ++mi)
            a4[mi] = *(const float4*)&xs[(tm * 4 + mi) * XSTR + k0];
        #pragma unroll
        for (int kk = 0; kk < 4; ++kk) {
            float4 w0 = *(const float4*)&W1[(size_t)(k0 + kk) * HID + tn * 8];
            float4 w1 = *(const float4*)&W1[(size_t)(k0 + kk) * HID + tn * 8 + 4];
            #pragma unroll
            for (int mi = 0; mi < 4; ++mi) {
                float a = F4C(a4[mi], kk);
                acc[mi][0] = fmaf(a, w0.x, acc[mi][0]);
                acc[mi][1] = fmaf(a, w0.y, acc[mi][1]);
                acc[mi][2] = fmaf(a, w0.z, acc[mi][2]);
                acc[mi][3] = fmaf(a, w0.w, acc[mi][3]);
                acc[mi][4] = fmaf(a, w1.x, acc[mi][4]);
                acc[mi][5] = fmaf(a, w1.y, acc[mi][5]);
                acc[mi][6] = fmaf(a, w1.z, acc[mi][6]);
                acc[mi][7] = fmaf(a, w1.w, acc[mi][7]);
            }
        }
    }
    // relu + store hidden into LDS (reuse xs)
    __syncthreads();   // all X reads done before overwrite
    #pragma unroll
    for (int mi = 0; mi < 4; ++mi) {
        float4 h0 = make_float4(fmaxf(acc[mi][0], 0.f), fmaxf(acc[mi][1], 0.f),
                                fmaxf(acc[mi][2], 0.f), fmaxf(acc[mi][3], 0.f));
        float4 h1 = make_float4(fmaxf(acc[mi][4], 0.f), fmaxf(acc[mi][5], 0.f),
                                fmaxf(acc[mi][6], 0.f), fmaxf(acc[mi][7], 0.f));
        *(float4*)&xs[(tm * 4 + mi) * HSTR + tn * 8]     = h0;
        *(float4*)&xs[(tm * 4 + mi) * HSTR + tn * 8 + 4] = h1;
    }
    __syncthreads();

    // ---- GEMM2: msg = hidden @ W2 + b2, K=256 ----
    float acc2[4][8];
    #pragma unroll
    for (int mi = 0; mi < 4; ++mi)
        #pragma unroll
        for (int ni = 0; ni < 8; ++ni)
            acc2[mi][ni] = b2[tn * 8 + ni];

    for (int k0 = 0; k0 < HID; k0 += 4) {
        float4 a4[4];
        #pragma unroll
        for (int mi = 0; mi < 4; ++mi)
            a4[mi] = *(const float4*)&xs[(tm * 4 + mi) * HSTR + k0];
        #pragma unroll
        for (int kk = 0; kk < 4; ++kk) {
            float4 w0 = *(const float4*)&W2[(size_t)(k0 + kk) * HID + tn * 8];
            float4 w1 = *(const float4*)&W2[(size_t)(k0 + kk) * HID + tn * 8 + 4];
            #pragma unroll
            for (int mi = 0; mi < 4; ++mi) {
                float a = F4C(a4[mi], kk);
                acc2[mi][0] = fmaf(a, w0.x, acc2[mi][0]);
                acc2[mi][1] = fmaf(a, w0.y, acc2[mi][1]);
                acc2[mi][2] = fmaf(a, w0.z, acc2[mi][2]);
                acc2[mi][3] = fmaf(a, w0.w, acc2[mi][3]);
                acc2[mi][4] = fmaf(a, w1.x, acc2[mi][4]);
                acc2[mi][5] = fmaf(a, w1.y, acc2[mi][5]);
                acc2[mi][6] = fmaf(a, w1.z, acc2[mi][6]);
                acc2[mi][7] = fmaf(a, w1.w, acc2[mi][7]);
            }
        }
    }

    // ---- scatter-add into agg[b, dst, :] ----
    #pragma unroll
    for (int mi = 0; mi < 4; ++mi) {
        int d = s_dst[tm * 4 + mi];
        float* base = agg + ((size_t)b * NC + d) * HID + tn * 8;
        #pragma unroll
        for (int ni = 0; ni < 8; ++ni)
            atomicAdd(base + ni, acc2[mi][ni]);
    }
}

__global__ __launch_bounds__(256)
void node_kernel(const float* __restrict__ cell_x,
                 const float* __restrict__ agg,
                 const float* __restrict__ counts,
                 const float* __restrict__ W1, const float* __restrict__ b1,
                 const float* __restrict__ W2, const float* __restrict__ b2,
                 const float* __restrict__ gamma, const float* __restrict__ beta,
                 float* __restrict__ out) {
    __shared__ float xs[MN * XSTR2];      // [cell_x | agg_mean], cell part stays live
    __shared__ float hid[MN * HSTR];      // hidden, later reused for h = cell_x + out
    __shared__ float s_inv[MN];

    const int tid = threadIdx.x;
    const int b   = blockIdx.x >> 8;              // 256 blocks per batch
    const int r0  = (blockIdx.x & 255) * MN;

    if (tid < MN) {
        float c = counts[b * NC + r0 + tid];
        s_inv[tid] = 1.0f / fmaxf(c, 1.0f);
    }
    __syncthreads();

    const int wv = tid >> 6, ln = tid & 63;
    #pragma unroll
    for (int i = 0; i < 4; ++i) {
        int m = wv * 4 + i;
        const float4* crow = (const float4*)(cell_x + ((size_t)b * NC + r0 + m) * HID);
        ((float4*)&xs[m * XSTR2])[ln] = crow[ln];
        const float4* grow = (const float4*)(agg + ((size_t)b * NC + r0 + m) * HID);
        float4 g = grow[ln];
        float inv = s_inv[m];
        g.x *= inv; g.y *= inv; g.z *= inv; g.w *= inv;
        ((float4*)&xs[m * XSTR2 + HID])[ln] = g;
    }
    __syncthreads();

    const int tn = tid & 31, tm = tid >> 5;   // 32 col-groups x 8 row-groups, 2 rows each
    // ---- GEMM1: hidden = relu(U @ W1 + b1), K=512 ----
    float acc[2][8];
    #pragma unroll
    for (int mi = 0; mi < 2; ++mi)
        #pragma unroll
        for (int ni = 0; ni < 8; ++ni)
            acc[mi][ni] = b1[tn * 8 + ni];

    for (int k0 = 0; k0 < 2 * HID; k0 += 4) {
        float4 a4[2];
        #pragma unroll
        for (int mi = 0; mi < 2; ++mi)
            a4[mi] = *(const float4*)&xs[(tm * 2 + mi) * XSTR2 + k0];
        #pragma unroll
        for (int kk = 0; kk < 4; ++kk) {
            float4 w0 = *(const float4*)&W1[(size_t)(k0 + kk) * HID + tn * 8];
            float4 w1 = *(const float4*)&W1[(size_t)(k0 + kk) * HID + tn * 8 + 4];
            #pragma unroll
            for (int mi = 0; mi < 2; ++mi) {
                float a = F4C(a4[mi], kk);
                acc[mi][0] = fmaf(a, w0.x, acc[mi][0]);
                acc[mi][1] = fmaf(a, w0.y, acc[mi][1]);
                acc[mi][2] = fmaf(a, w0.z, acc[mi][2]);
                acc[mi][3] = fmaf(a, w0.w, acc[mi][3]);
                acc[mi][4] = fmaf(a, w1.x, acc[mi][4]);
                acc[mi][5] = fmaf(a, w1.y, acc[mi][5]);
                acc[mi][6] = fmaf(a, w1.z, acc[mi][6]);
                acc[mi][7] = fmaf(a, w1.w, acc[mi][7]);
            }
        }
    }
    #pragma unroll
    for (int mi = 0; mi < 2; ++mi) {
        float4 h0 = make_float4(fmaxf(acc[mi][0], 0.f), fmaxf(acc[mi][1], 0.f),
                                fmaxf(acc[mi][2], 0.f), fmaxf(acc[mi][3], 0.f));
        float4 h1 = make_float4(fmaxf(acc[mi][4], 0.f), fmaxf(acc[mi][5], 0.f),
                                fmaxf(acc[mi][6], 0.f), fmaxf(acc[mi][7], 0.f));
        *(float4*)&hid[(tm * 2 + mi) * HSTR + tn * 8]     = h0;
        *(float4*)&hid[(tm * 2 + mi) * HSTR + tn * 8 + 4] = h1;
    }
    __syncthreads();

    // ---- GEMM2: o = hidden @ W2 + b2, K=256 ----
    float acc2[2][8];
    #pragma unroll
    for (int mi = 0; mi < 2; ++mi)
        #pragma unroll
        for (int ni = 0; ni < 8; ++ni)
            acc2[mi][ni] = b2[tn * 8 + ni];

    for (int k0 = 0; k0 < HID; k0 += 4) {
        float4 a4[2];
        #pragma unroll
        for (int mi = 0; mi < 2; ++mi)
            a4[mi] = *(const float4*)&hid[(tm * 2 + mi) * HSTR + k0];
        #pragma unroll
        for (int kk = 0; kk < 4; ++kk) {
            float4 w0 = *(const float4*)&W2[(size_t)(k0 + kk) * HID + tn * 8];
            float4 w1 = *(const float4*)&W2[(size_t)(k0 + kk) * HID + tn * 8 + 4];
            #pragma unroll
            for (int mi = 0; mi < 2; ++mi) {
                float a = F4C(a4[mi], kk);
                acc2[mi][0] = fmaf(a, w0.x, acc2[mi][0]);
                acc2[mi][1] = fmaf(a, w0.y, acc2[mi][1]);
                acc2[mi][2] = fmaf(a, w0.z, acc2[mi][2]);
                acc2[mi][3] = fmaf(a, w0.w, acc2[mi][3]);
                acc2[mi][4] = fmaf(a, w1.x, acc2[mi][4]);
                acc2[mi][5] = fmaf(a, w1.y, acc2[mi][5]);
                acc2[mi][6] = fmaf(a, w1.z, acc2[mi][6]);
                acc2[mi][7] = fmaf(a, w1.w, acc2[mi][7]);
            }
        }
    }
    __syncthreads();   // all hidden reads done; reuse hid for h = cell_x + o

    #pragma unroll
    for (int mi = 0; mi < 2; ++mi) {
        int m = tm * 2 + mi;
        #pragma unroll
        for (int ni = 0; ni < 8; ++ni) {
            int c = tn * 8 + ni;
            hid[m * HSTR + c] = acc2[mi][ni] + xs[m * XSTR2 + c];
        }
    }
    __syncthreads();

    // ---- LayerNorm per row: wave wv handles rows wv*4 .. wv*4+3 ----
    for (int i = 0; i < 4; ++i) {
        int r = wv * 4 + i;
        float v[4];
        float s = 0.f, q = 0.f;
        #pragma unroll
        for (int j = 0; j < 4; ++j) {
            v[j] = hid[r * HSTR + ln + 64 * j];
            s += v[j];
            q = fmaf(v[j], v[j], q);
        }
        #pragma unroll
        for (int off = 32; off > 0; off >>= 1) {
            s += __shfl_xor(s, off, 64);
            q += __shfl_xor(q, off, 64);
        }
        float mu = s * (1.0f / HID);
        float var = q * (1.0f / HID) - mu * mu;
        float rs = rsqrtf(var + EPSV);
        float* orow = out + ((size_t)b * NC + r0 + r) * HID;
        #pragma unroll
        for (int j = 0; j < 4; ++j) {
            int c = ln + 64 * j;
            orow[c] = (v[j] - mu) * rs * gamma[c] + beta[c];
        }
    }
}

extern "C" void kernel_launch(void* const* d_in, const int* in_sizes, int n_in,
                              void* d_out, int out_size, void* d_ws, size_t ws_size,
                              hipStream_t stream) {
    const float* cell_x = (const float*)d_in[0];
    const int*   eidx   = (const int*)d_in[1];
    const float* eattr  = (const float*)d_in[2];
    const float* mW1    = (const float*)d_in[3];
    const float* mb1    = (const float*)d_in[4];
    const float* mW2    = (const float*)d_in[5];
    const float* mb2    = (const float*)d_in[6];
    const float* uW1    = (const float*)d_in[7];
    const float* ub1    = (const float*)d_in[8];
    const float* uW2    = (const float*)d_in[9];
    const float* ub2    = (const float*)d_in[10];
    const float* gamma  = (const float*)d_in[11];
    const float* beta   = (const float*)d_in[12];
    float* out = (float*)d_out;

    float* agg    = (float*)d_ws;                        // [B, NC, HID]
    float* counts = agg + (size_t)BSZ * NC * HID;        // [B, NC]

    int n4 = (BSZ * NC * HID + BSZ * NC) / 4;
    zero_kernel<<<512, 256, 0, stream>>>((float4*)d_ws, n4);
    count_kernel<<<(BSZ * NE) / 256, 256, 0, stream>>>(eidx, counts);
    edge_kernel<<<BSZ * NE / ME, 256, 0, stream>>>(cell_x, eidx, eattr,
                                                   mW1, mb1, mW2, mb2, agg);
    node_kernel<<<BSZ * NC / MN, 256, 0, stream>>>(cell_x, agg, counts,
                                                   uW1, ub1, uW2, ub2,
                                                   gamma, beta, out);
}